// Round 6
// baseline (217.318 us; speedup 1.0000x reference)
//
#include <hip/hip_runtime.h>
#include <hip/hip_bf16.h>
#include <math.h>

#define RR 1024
#define BB 16
#define DD 1024
#define K_ACTIVE 20

typedef float vfloat4 __attribute__((ext_vector_type(4)));

// ---------------------------------------------------------------------------
// Kernel 1: adj[b,r] = dot(H[r,b,:],w) - theta[r] - refr[b,r]
//                      - 0.5*(0.9*fb[b,r] + 0.1*||msg[r,b,:]||)
// One wave per pair (4096 blocks x 4 waves). The sched_barrier(0) pins all
// 12 dwordx4 loads BEFORE any compute: the scheduler cannot re-sink them to
// shrink live ranges (the R1/R3/R5 failure mode: ~3 loads in flight, 48 us).
// 12 KB in flight per wave x 16 waves/CU = 192 KB/CU -> BW-limited.
// ---------------------------------------------------------------------------
__global__ __launch_bounds__(256, 4) void score_kernel(
    const float* __restrict__ H, const float* __restrict__ msg,
    const float* __restrict__ w, const float* __restrict__ theta,
    const float* __restrict__ refr, const float* __restrict__ fb,
    float* __restrict__ adj_out)
{
    const int wave = threadIdx.x >> 6;
    const int lane = threadIdx.x & 63;
    const int pair = blockIdx.x * 4 + wave;   // pair = r*BB + b
    const int r = pair >> 4;
    const int b = pair & 15;

    const vfloat4* __restrict__ H4 = (const vfloat4*)(H + (size_t)pair * DD);
    const vfloat4* __restrict__ M4 = (const vfloat4*)(msg + (size_t)pair * DD);
    const vfloat4* __restrict__ W4 = (const vfloat4*)w;

    // --- load block: 12 independent global_load_dwordx4 ---
    const vfloat4 h0 = H4[lane],       h1 = H4[lane + 64];
    const vfloat4 h2 = H4[lane + 128], h3 = H4[lane + 192];
    const vfloat4 m0 = M4[lane],       m1 = M4[lane + 64];
    const vfloat4 m2 = M4[lane + 128], m3 = M4[lane + 192];
    const vfloat4 w0 = W4[lane],       w1 = W4[lane + 64];
    const vfloat4 w2 = W4[lane + 128], w3 = W4[lane + 192];

    // Scheduler fence: nothing moves across. Forces all 12 loads issued
    // before the first FMA (VGPR cost ~80 -> still 4 waves/EU at <=128).
    __builtin_amdgcn_sched_barrier(0);

    float dot = h0.x * w0.x + h0.y * w0.y + h0.z * w0.z + h0.w * w0.w;
    dot += h1.x * w1.x + h1.y * w1.y + h1.z * w1.z + h1.w * w1.w;
    dot += h2.x * w2.x + h2.y * w2.y + h2.z * w2.z + h2.w * w2.w;
    dot += h3.x * w3.x + h3.y * w3.y + h3.z * w3.z + h3.w * w3.w;

    float ss = m0.x * m0.x + m0.y * m0.y + m0.z * m0.z + m0.w * m0.w;
    ss += m1.x * m1.x + m1.y * m1.y + m1.z * m1.z + m1.w * m1.w;
    ss += m2.x * m2.x + m2.y * m2.y + m2.z * m2.z + m2.w * m2.w;
    ss += m3.x * m3.x + m3.y * m3.y + m3.z * m3.z + m3.w * m3.w;

#pragma unroll
    for (int off = 32; off > 0; off >>= 1) {
        dot += __shfl_down(dot, off);
        ss  += __shfl_down(ss, off);
    }
    if (lane == 0) {
        const float fb_mag = sqrtf(ss);
        const float fb_new = 0.9f * fb[b * RR + r] + 0.1f * fb_mag;
        adj_out[b * RR + r] = dot - theta[r] - refr[b * RR + r] - 0.5f * fb_new;
    }
}

// ---------------------------------------------------------------------------
// Kernel 2: greedy hex NMS — ONE WAVE per batch (16 blocks x 64 threads).
// Equivalent to the reference scan over argsort(-adj): iterated argmax over
// non-suppressed entries, tie -> lowest index (stable sort order).
// ---------------------------------------------------------------------------
__global__ __launch_bounds__(64) void nms_kernel(
    const float* __restrict__ adj, const int* __restrict__ nbrs,
    float* __restrict__ hard)
{
    __shared__ float val[RR];
    __shared__ int   nb[RR * 6];
    __shared__ unsigned char sel[RR];

    const int b = blockIdx.x;
    const int lane = threadIdx.x;   // 0..63

#pragma unroll
    for (int j = 0; j < 16; ++j) {
        const int i = lane + 64 * j;
        val[i] = adj[b * RR + i];
        sel[i] = 0;
    }
    const int4* nb4g = (const int4*)nbrs;
    int4* nb4s = (int4*)nb;
#pragma unroll
    for (int j = 0; j < 24; ++j)
        nb4s[lane + 64 * j] = nb4g[lane + 64 * j];
    __syncthreads();

    for (int it = 0; it < K_ACTIVE; ++it) {
        float m = -INFINITY;
        int mi = RR;
#pragma unroll
        for (int j = 0; j < 16; ++j) {
            const int i = lane + 64 * j;
            const float v = val[i];
            if (v > m || (v == m && i < mi)) { m = v; mi = i; }
        }
#pragma unroll
        for (int off = 32; off > 0; off >>= 1) {
            const float ov = __shfl_down(m, off);
            const int   oi = __shfl_down(mi, off);
            if (ov > m || (ov == m && oi < mi)) { m = ov; mi = oi; }
        }
        const int   bi = __shfl(mi, 0);
        const float bm = __shfl(m, 0);
        if (bm > -INFINITY) {
            if (lane == 0) { sel[bi] = 1; val[bi] = -INFINITY; }
            if (lane < 6)  { val[nb[bi * 6 + lane]] = -INFINITY; }
        }
        __syncthreads();
    }

#pragma unroll
    for (int j = 0; j < 16; ++j) {
        const int i = lane + 64 * j;
        hard[b * RR + i] = sel[i] ? 1.0f : 0.0f;
    }
}

// ---------------------------------------------------------------------------
// Kernel 3 (scatter): Hs was already zeroed by hipMemsetAsync; only copy the
// ~320 active rows (hard[b,r]==1, ~2%). One wave per pair; inactive waves
// exit after one scalar load. Write traffic for inactive rows: zero.
// ---------------------------------------------------------------------------
__global__ __launch_bounds__(64) void scatter_kernel(
    const float* __restrict__ H, const float* __restrict__ hard,
    float* __restrict__ Hs)
{
    const int pair = blockIdx.x;   // pair = r*BB + b
    const int r = pair >> 4;
    const int b = pair & 15;
    if (hard[b * RR + r] == 0.0f) return;

    const int lane = threadIdx.x;
    const vfloat4* __restrict__ H4 = (const vfloat4*)(H + (size_t)pair * DD);
    vfloat4* out4 = (vfloat4*)(Hs + (size_t)pair * DD);
    const vfloat4 v0 = H4[lane],       v1 = H4[lane + 64];
    const vfloat4 v2 = H4[lane + 128], v3 = H4[lane + 192];
    out4[lane]       = v0;
    out4[lane + 64]  = v1;
    out4[lane + 128] = v2;
    out4[lane + 192] = v3;
}

extern "C" void kernel_launch(void* const* d_in, const int* in_sizes, int n_in,
                              void* d_out, int out_size, void* d_ws, size_t ws_size,
                              hipStream_t stream) {
    const float* H     = (const float*)d_in[0];   // [R,B,D]
    const float* msg   = (const float*)d_in[1];   // [R,B,D]
    const float* w     = (const float*)d_in[2];   // [D]
    const float* theta = (const float*)d_in[3];   // [R]
    const float* refr  = (const float*)d_in[4];   // [B,R]
    const float* fb    = (const float*)d_in[5];   // [B,R]
    const int*   nbrs  = (const int*)d_in[6];     // [R,6]

    float* out  = (float*)d_out;
    float* Hs   = out;                                   // [R,B,D]
    float* hard = out + (size_t)RR * BB * DD;            // [B,R]
    float* adj  = hard + (size_t)BB * RR;                // [B,R]

    // Zero the Hs region up front (pure fill, no read: ~5 TB/s blit rate).
    // hard/adj are fully overwritten by nms/score, no memset needed.
    hipMemsetAsync(Hs, 0, (size_t)RR * BB * DD * sizeof(float), stream);

    score_kernel<<<RR * BB / 4, 256, 0, stream>>>(H, msg, w, theta, refr, fb, adj);
    nms_kernel<<<BB, 64, 0, stream>>>(adj, nbrs, hard);
    scatter_kernel<<<RR * BB, 64, 0, stream>>>(H, hard, Hs);
}